// Round 4
// baseline (1456.963 us; speedup 1.0000x reference)
//
#include <hip/hip_runtime.h>
#include <hip/hip_bf16.h>
#include <math.h>

#define DD 512
#define LL 256
#define CC 128
#define ROWS 2048  // B*C = 16*128

typedef __attribute__((ext_vector_type(8))) __bf16 bf16x8;
typedef __attribute__((ext_vector_type(4))) float f32x4;

// ---------------- Kernel 1: masked mean over L ----------------
// E[row,:] = sum_l mask[row,l]*x[row,l,:] / max(sum_l mask[row,l], 1)
__global__ void k_masked_mean(const float* __restrict__ x, const float* __restrict__ mask,
                              float* __restrict__ E, __hip_bfloat16* __restrict__ Eb,
                              float* __restrict__ msum) {
    int row = blockIdx.x;
    int t = threadIdx.x;  // 0..255
    __shared__ float mlds[LL];
    __shared__ float red[256];
    __shared__ float4 comb[128];

    float mv = mask[(size_t)row * LL + t];
    mlds[t] = mv;
    red[t] = mv;
    __syncthreads();
    for (int s = 128; s > 0; s >>= 1) {
        if (t < s) red[t] += red[t + s];
        __syncthreads();
    }
    float total = red[0];
    float denom = 1.0f / fmaxf(total, 1.0f);
    if (t == 0) msum[row] = total;

    int c4 = t & 127;     // float4 column
    int half = t >> 7;    // 0 or 1
    const f32x4* x4 = (const f32x4*)(x + (size_t)row * LL * DD);
    float ax = 0, ay = 0, az = 0, aw = 0;
#pragma unroll 4
    for (int l = half; l < LL; l += 2) {
        float w = mlds[l];
        f32x4 v = __builtin_nontemporal_load(&x4[(size_t)l * 128 + c4]);
        ax += w * v.x; ay += w * v.y; az += w * v.z; aw += w * v.w;
    }
    if (half) comb[c4] = make_float4(ax, ay, az, aw);
    __syncthreads();
    if (!half) {
        float4 o = comb[c4];
        ax = (ax + o.x) * denom;
        ay = (ay + o.y) * denom;
        az = (az + o.z) * denom;
        aw = (aw + o.w) * denom;
        ((float4*)(E + (size_t)row * DD))[c4] = make_float4(ax, ay, az, aw);
        __hip_bfloat16* eb = Eb + (size_t)row * DD + c4 * 4;
        eb[0] = __float2bfloat16(ax);
        eb[1] = __float2bfloat16(ay);
        eb[2] = __float2bfloat16(az);
        eb[3] = __float2bfloat16(aw);
    }
}

// ---------------- Kernel 2: fused tiled transpose + cast to bf16 ----------------
// One launch handles all 4 weights. 32x32 tiles through padded LDS:
// coalesced reads along n, coalesced writes along k, conflict-free LDS.
// blockIdx.y = weight id (0:Wqkv 1:Wo 2:W1 3:W2)
__global__ void k_transpose_cast_all(const float* __restrict__ Wqkv, const float* __restrict__ Wo,
                                     const float* __restrict__ W1, const float* __restrict__ W2,
                                     __hip_bfloat16* __restrict__ WqkvT, __hip_bfloat16* __restrict__ WoT,
                                     __hip_bfloat16* __restrict__ W1T, __hip_bfloat16* __restrict__ W2T) {
    const int Ks[4] = {512, 512, 512, 1024};
    const int Ns[4] = {1536, 512, 1024, 512};
    int w = blockIdx.y;
    int K = Ks[w], N = Ns[w];
    int ntiles_n = N >> 5;
    int ntiles = ntiles_n * (K >> 5);
    if (blockIdx.x >= (unsigned)ntiles) return;
    const float* src = (w == 0) ? Wqkv : (w == 1) ? Wo : (w == 2) ? W1 : W2;
    __hip_bfloat16* dst = (w == 0) ? WqkvT : (w == 1) ? WoT : (w == 2) ? W1T : W2T;

    int tn = blockIdx.x % ntiles_n;
    int tk = blockIdx.x / ntiles_n;
    int n0 = tn << 5;
    int k0 = tk << 5;

    __shared__ float lds[32][33];
    int tx = threadIdx.x & 31;
    int ty = threadIdx.x >> 5;  // 0..7
#pragma unroll
    for (int r = 0; r < 4; r++) {
        int kl = ty + r * 8;
        lds[kl][tx] = src[(size_t)(k0 + kl) * N + n0 + tx];
    }
    __syncthreads();
#pragma unroll
    for (int r = 0; r < 4; r++) {
        int nl = ty + r * 8;
        dst[(size_t)(n0 + nl) * K + k0 + tx] = __float2bfloat16(lds[tx][nl]);
    }
}

// ---------------- Kernel 3: bf16 MFMA GEMM, C = A * BT^T + bias ----------------
// A: M x K bf16 row-major. BT: N x K bf16 row-major. Output f32 (GELU_BF16=0) or gelu->bf16 (=1).
// Block 256 = 4 waves; block computes 64x64 tile; wave w -> rows [w*16, w*16+16), 64 cols.
// N,K compile-time -> full K-unroll, batched loads, const-folded addressing.
// MFMA 16x16x32 layouts (HW-verified): A: m=lane&15, k=quad*8+j; B: n=lane&15, k=quad*8+j;
// C/D: col=lane&15, row=quad*4+reg.
template <int GELU_BF16, int N, int K>
__global__ void k_gemm_bt(const __hip_bfloat16* __restrict__ A, const __hip_bfloat16* __restrict__ BT,
                          const float* __restrict__ bias, float* __restrict__ Cf,
                          __hip_bfloat16* __restrict__ Cb) {
    int wave = threadIdx.x >> 6;
    int lane = threadIdx.x & 63;
    int m0 = blockIdx.y * 64 + wave * 16;
    int n0 = blockIdx.x * 64;
    int mrow = lane & 15;
    int quad = lane >> 4;

    const __bf16* Ab = (const __bf16*)A;
    const __bf16* Bb = (const __bf16*)BT;

    f32x4 acc0 = {0.f, 0.f, 0.f, 0.f};
    f32x4 acc1 = {0.f, 0.f, 0.f, 0.f};
    f32x4 acc2 = {0.f, 0.f, 0.f, 0.f};
    f32x4 acc3 = {0.f, 0.f, 0.f, 0.f};

    const __bf16* arow = Ab + (size_t)(m0 + mrow) * K + quad * 8;
    const __bf16* b0p = Bb + (size_t)(n0 + mrow) * K + quad * 8;
    const __bf16* b1p = b0p + (size_t)16 * K;
    const __bf16* b2p = b0p + (size_t)32 * K;
    const __bf16* b3p = b0p + (size_t)48 * K;

#pragma unroll
    for (int k0 = 0; k0 < K; k0 += 32) {
        bf16x8 a  = *(const bf16x8*)(arow + k0);
        bf16x8 b0 = *(const bf16x8*)(b0p + k0);
        bf16x8 b1 = *(const bf16x8*)(b1p + k0);
        bf16x8 b2 = *(const bf16x8*)(b2p + k0);
        bf16x8 b3 = *(const bf16x8*)(b3p + k0);
        acc0 = __builtin_amdgcn_mfma_f32_16x16x32_bf16(a, b0, acc0, 0, 0, 0);
        acc1 = __builtin_amdgcn_mfma_f32_16x16x32_bf16(a, b1, acc1, 0, 0, 0);
        acc2 = __builtin_amdgcn_mfma_f32_16x16x32_bf16(a, b2, acc2, 0, 0, 0);
        acc3 = __builtin_amdgcn_mfma_f32_16x16x32_bf16(a, b3, acc3, 0, 0, 0);
    }

    int col = lane & 15;
    int rbase = quad * 4;
    f32x4 accs[4] = {acc0, acc1, acc2, acc3};
#pragma unroll
    for (int tIdx = 0; tIdx < 4; tIdx++) {
#pragma unroll
        for (int r = 0; r < 4; r++) {
            int gr = m0 + rbase + r;
            int gc = n0 + tIdx * 16 + col;
            float v = accs[tIdx][r] + bias[gc];
            if (GELU_BF16) {
                v = 0.5f * v * (1.0f + erff(v * 0.70710678118654752f));
                Cb[(size_t)gr * N + gc] = __float2bfloat16(v);
            } else {
                Cf[(size_t)gr * N + gc] = v;
            }
        }
    }
}

// ---------------- Kernel 4: attention per (b,c) row ----------------
// 16 lanes cooperate per e-row (coalesced 256B slices per group),
// 4-step shfl_xor butterfly for the row reduction, all f32 math.
__global__ void k_attn(const float* __restrict__ qkv, const float* __restrict__ mask,
                       const float* __restrict__ msum, __hip_bfloat16* __restrict__ attnb) {
    int row = blockIdx.x;          // b*CC + c
    int b = row >> 7;
    int t = threadIdx.x;           // 0..255
    int wave = t >> 6;             // 0..3
    int lane = t & 63;
    int g = lane >> 4;             // group within wave: 0..3
    int s = lane & 15;             // lane within group: 0..15
    __shared__ float Sv[CC];
    __shared__ float red[256];

    // Preload q (512 floats) and mask_c (256 floats) chunks into registers.
    const float4* q4 = (const float4*)(qkv + (size_t)row * 1536);
    float4 qr[8];
#pragma unroll
    for (int j = 0; j < 8; j++) qr[j] = q4[j * 16 + s];
    const float4* mr4 = (const float4*)(mask + (size_t)row * LL);
    float4 mr[4];
#pragma unroll
    for (int j = 0; j < 4; j++) mr[j] = mr4[j * 16 + s];
    float mtot_c = msum[row];

    // 128 e-rows over 4 waves x 4 groups -> 8 iterations
#pragma unroll 2
    for (int i = 0; i < 8; i++) {
        int e = i * 16 + wave * 4 + g;
        const float4* k4 = (const float4*)(qkv + (size_t)(b * CC + e) * 1536 + 512);
        const float4* me4 = (const float4*)(mask + (size_t)(b * CC + e) * LL);
        float part = 0.0f, jpart = 0.0f;
#pragma unroll
        for (int j = 0; j < 8; j++) {
            float4 kk = k4[j * 16 + s];
            part += qr[j].x * kk.x + qr[j].y * kk.y + qr[j].z * kk.z + qr[j].w * kk.w;
        }
#pragma unroll
        for (int j = 0; j < 4; j++) {
            float4 mm = me4[j * 16 + s];
            jpart += mr[j].x * mm.x + mr[j].y * mm.y + mr[j].z * mm.z + mr[j].w * mm.w;
        }
        // butterfly within the 16-lane group (masks < 16 never cross groups)
#pragma unroll
        for (int off = 8; off > 0; off >>= 1) {
            part += __shfl_xor(part, off);
            jpart += __shfl_xor(jpart, off);
        }
        if (s == 0) {
            float tp = mtot_c + msum[b * CC + e];
            float overlap = 2.0f * jpart / fmaxf(tp, 1.0f);
            Sv[e] = part * 0.044194173824159216f * (0.5f + 0.5f * overlap);
        }
    }
    __syncthreads();

    // softmax over 128 entries
    float v = (t < CC) ? Sv[t] : -INFINITY;
    red[t] = v;
    __syncthreads();
    for (int st = 128; st > 0; st >>= 1) {
        if (t < st) red[t] = fmaxf(red[t], red[t + st]);
        __syncthreads();
    }
    float mx = red[0];
    __syncthreads();
    float p = (t < CC) ? expf(v - mx) : 0.0f;
    red[t] = p;
    __syncthreads();
    for (int st = 128; st > 0; st >>= 1) {
        if (t < st) red[t] += red[t + st];
        __syncthreads();
    }
    float Z = red[0];
    __syncthreads();
    if (t < CC) Sv[t] = p / Z;
    __syncthreads();

    // attn_out[row, 2t:2t+2] = sum_e A[e] * v[b,e,2t:2t+2]  (float2 loads, bf16x2 store)
    const float2* v2 = (const float2*)(qkv + (size_t)(b * CC) * 1536 + 1024);
    float a0 = 0.0f, a1 = 0.0f;
#pragma unroll 8
    for (int e2 = 0; e2 < CC; e2++) {
        float a = Sv[e2];
        float2 vv = v2[(size_t)e2 * 768 + t];
        a0 += a * vv.x;
        a1 += a * vv.y;
    }
    __hip_bfloat162* out2 = (__hip_bfloat162*)(attnb + (size_t)row * DD);
    __hip_bfloat162 o2;
    o2.x = __float2bfloat16(a0);
    o2.y = __float2bfloat16(a1);
    out2[t] = o2;
}

// ---------------- Kernel 5: residual add + LayerNorm ----------------
template <int WRITE_BF16>
__global__ void k_add_ln(const float* __restrict__ X, const float* __restrict__ Y,
                         const float* __restrict__ g, const float* __restrict__ be,
                         float* __restrict__ Of, __hip_bfloat16* __restrict__ Ob) {
    int row = blockIdx.x;
    int t = threadIdx.x;  // 0..255, two elems per thread
    __shared__ float red[256];
    const float* xr = X + (size_t)row * DD;
    const float* yr = Y + (size_t)row * DD;
    float v0 = xr[t] + yr[t];
    float v1 = xr[t + 256] + yr[t + 256];
    red[t] = v0 + v1;
    __syncthreads();
    for (int s = 128; s > 0; s >>= 1) {
        if (t < s) red[t] += red[t + s];
        __syncthreads();
    }
    float mu = red[0] * (1.0f / 512.0f);
    __syncthreads();
    float d0 = v0 - mu, d1 = v1 - mu;
    red[t] = d0 * d0 + d1 * d1;
    __syncthreads();
    for (int s = 128; s > 0; s >>= 1) {
        if (t < s) red[t] += red[t + s];
        __syncthreads();
    }
    float var = red[0] * (1.0f / 512.0f);
    float rs = rsqrtf(var + 1e-5f);
    float o0 = d0 * rs * g[t] + be[t];
    float o1 = d1 * rs * g[t + 256] + be[t + 256];
    Of[(size_t)row * DD + t] = o0;
    Of[(size_t)row * DD + t + 256] = o1;
    if (WRITE_BF16) {
        Ob[(size_t)row * DD + t] = __float2bfloat16(o0);
        Ob[(size_t)row * DD + t + 256] = __float2bfloat16(o1);
    }
}

extern "C" void kernel_launch(void* const* d_in, const int* in_sizes, int n_in,
                              void* d_out, int out_size, void* d_ws, size_t ws_size,
                              hipStream_t stream) {
    const float* x    = (const float*)d_in[0];
    const float* mask = (const float*)d_in[1];
    const float* Wqkv = (const float*)d_in[2];
    const float* bqkv = (const float*)d_in[3];
    const float* Wo   = (const float*)d_in[4];
    const float* bo   = (const float*)d_in[5];
    const float* W1   = (const float*)d_in[6];
    const float* b1   = (const float*)d_in[7];
    const float* W2   = (const float*)d_in[8];
    const float* b2   = (const float*)d_in[9];
    const float* g1   = (const float*)d_in[10];
    const float* be1  = (const float*)d_in[11];
    const float* g2   = (const float*)d_in[12];
    const float* be2  = (const float*)d_in[13];
    float* out = (float*)d_out;

    char* ws = (char*)d_ws;
    size_t off = 0;
    auto alloc = [&](size_t bytes) -> void* {
        void* p = ws + off;
        off = (off + bytes + 255) & ~(size_t)255;
        return p;
    };
    float* E            = (float*)alloc((size_t)ROWS * DD * 4);
    __hip_bfloat16* Eb  = (__hip_bfloat16*)alloc((size_t)ROWS * DD * 2);
    float* msum         = (float*)alloc((size_t)ROWS * 4);
    float* qkv          = (float*)alloc((size_t)ROWS * 1536 * 4);
    __hip_bfloat16* WqkvT = (__hip_bfloat16*)alloc((size_t)1536 * 512 * 2);
    __hip_bfloat16* WoT   = (__hip_bfloat16*)alloc((size_t)512 * 512 * 2);
    __hip_bfloat16* W1T   = (__hip_bfloat16*)alloc((size_t)1024 * 512 * 2);
    __hip_bfloat16* W2T   = (__hip_bfloat16*)alloc((size_t)512 * 1024 * 2);
    __hip_bfloat16* attnb = (__hip_bfloat16*)alloc((size_t)ROWS * DD * 2);
    float* o            = (float*)alloc((size_t)ROWS * DD * 4);
    float* E2           = (float*)alloc((size_t)ROWS * DD * 4);
    __hip_bfloat16* E2b = (__hip_bfloat16*)alloc((size_t)ROWS * DD * 2);
    __hip_bfloat16* hb  = (__hip_bfloat16*)alloc((size_t)ROWS * 1024 * 2);
    float* h2           = (float*)alloc((size_t)ROWS * DD * 4);

    // 1. masked mean
    k_masked_mean<<<ROWS, 256, 0, stream>>>(x, mask, E, Eb, msum);
    // 2. fused weight transpose+cast (one launch, 4 weights)
    k_transpose_cast_all<<<dim3(768, 4), 256, 0, stream>>>(Wqkv, Wo, W1, W2, WqkvT, WoT, W1T, W2T);
    // 3. qkv = E @ Wqkv + bqkv
    k_gemm_bt<0, 1536, 512><<<dim3(1536 / 64, ROWS / 64), 256, 0, stream>>>(Eb, WqkvT, bqkv, qkv, nullptr);
    // 4. attention (scores, overlap, softmax, A@v)
    k_attn<<<ROWS, 256, 0, stream>>>(qkv, mask, msum, attnb);
    // 5. o = attn @ Wo + bo
    k_gemm_bt<0, 512, 512><<<dim3(512 / 64, ROWS / 64), 256, 0, stream>>>(attnb, WoT, bo, o, nullptr);
    // 6. E2 = LN(E + o)
    k_add_ln<1><<<ROWS, 256, 0, stream>>>(E, o, g1, be1, E2, E2b);
    // 7. h = gelu(E2 @ W1 + b1) -> bf16
    k_gemm_bt<1, 1024, 512><<<dim3(1024 / 64, ROWS / 64), 256, 0, stream>>>(E2b, W1T, b1, nullptr, hb);
    // 8. h2 = h @ W2 + b2
    k_gemm_bt<0, 512, 1024><<<dim3(512 / 64, ROWS / 64), 256, 0, stream>>>(hb, W2T, b2, h2, nullptr);
    // 9. out = LN(E2 + h2)
    k_add_ln<0><<<ROWS, 256, 0, stream>>>(E2, h2, g2, be2, out, nullptr);
}